// Round 9
// baseline (2812.812 us; speedup 1.0000x reference)
//
#include <hip/hip_runtime.h>
#include <stdint.h>

// LSTM B=256,T=512,F=32,U=350; gates i,f,g(relu),o; h=o*relu(c); out=h.dw+db
//
// R9: dual-scope TAGGED h exchange. No flags, no fences, no placement trust.
//  - Both h buffers hold u32 words: hi16 = bf16(h), lo16 = step tag. Word-
//    atomic => a consumer's data load IS the sync; exact tag match required,
//    so stale data is always DETECTED (R8's silent-staleness bug fixed).
//  - Fast path: sc0 stores -> shared XCD-L2; consumer 22x dwordx4 sc0 burst
//    + tag check, <=256 retries. Cross-XCD placement => tags never match
//    (consumer L2 caches stale line) => sticky per-wave fallback.
//  - Safe path: R7's agent-scope tagged words (always dual-published,
//    fire-and-forget; h stores data-depend on the loads -> ordered).
//  - Ping-pong depth 2 induction unchanged; holds for mixed-path waves.
//  - Rest as R7: 16 groups x 11 col-blocks (2 waves/block); wave owns 16
//    cols x all 4 gates; weights reg-resident (waves_per_eu(1,1)); no
//    barriers in scan; dense head via LDS partials + reduce_out.

#define T_   512
#define F_   32
#define U_   350
#define G4   1400
#define NGRP 16
#define NB   16
#define NCB  11
#define KC   12
#define NT   88
#define HROW 352
#define MAXTRY 256

typedef __attribute__((ext_vector_type(8))) short  short8;
typedef __attribute__((ext_vector_type(4))) short  short4_;
typedef __attribute__((ext_vector_type(4))) float  float4_;
typedef __attribute__((ext_vector_type(4))) uint32_t u32x4;
typedef unsigned long long u64t;

__device__ __forceinline__ short f2bf(float f) {
  union { float f; uint32_t u; } v; v.f = f;
  return (short)((v.u + 0x7FFFu + ((v.u >> 16) & 1u)) >> 16);
}

// ---- workspace layout (bytes) ----
#define SZ_W      (NT*KC*64*8*2u)                       // 1,081,344
#define OFF_XBF   (SZ_W)
#define SZ_XBF    (256u*T_*F_*2u)                       // 8,388,608
#define OFF_HFA   (OFF_XBF + SZ_XBF)                    // fast: tagged, sc0
#define SZ_HFA    (NGRP*2u*NB*HROW*4u)                  // 720,896
#define OFF_HSA   (OFF_HFA + SZ_HFA)                    // safe: tagged, agent
#define SZ_HSA    (NGRP*2u*NB*HROW*4u)                  // 720,896
#define OFF_WP    (OFF_HSA + SZ_HSA)
#define SZ_WP     (NGRP*NCB*NB*T_*4u)                   // 5,767,168

// ---- prep: W_swz[kc][tile][lane][8] bf16 in MFMA B-fragment order ----
__global__ void prep_w(const float* __restrict__ kern,
                       const float* __restrict__ rk,
                       const float* __restrict__ bias,
                       short* __restrict__ wswz) {
  const int tile = blockIdx.x, lane = threadIdx.x;
  const int g = tile / 22, jt = tile % 22;
  const int colg = jt * 16 + (lane & 15);
  const int src = g * U_ + colg;
  const bool valid = (colg < U_);
  const int kbase = (lane >> 4) * 8;
  for (int kc = 0; kc < KC; ++kc) {
    short8 pack;
    #pragma unroll
    for (int jj = 0; jj < 8; ++jj) {
      int k = kc * 32 + kbase + jj;
      float v = 0.f;
      if (valid) {
        if (k < F_)            v = kern[k * G4 + src];
        else if (k < F_ + U_)  v = rk[(k - F_) * G4 + src];
        else if (k == F_ + U_) v = bias[src];
      }
      pack[jj] = f2bf(v);
    }
    *(short8*)(wswz + (((size_t)kc * NT + tile) * 64 + lane) * 8) = pack;
  }
}

// ---- prep: x f32 -> bf16 ([b][t][f], contiguous 16B A-frag loads) ----
__global__ void prep_x(const float* __restrict__ x, short* __restrict__ xbf) {
  int i = (blockIdx.x * 256 + threadIdx.x) * 4;
  float4_ v = *(const float4_*)(x + i);
  short4_ o;
  #pragma unroll
  for (int jj = 0; jj < 4; ++jj) o[jj] = f2bf(v[jj]);
  *(short4_*)(xbf + i) = o;
}

// ---- init: slot1 of BOTH buffers = h_{-1}=0 tag0 (+bf16 1.0 at col 350) ----
__global__ void init_all(uint32_t* __restrict__ hfa, uint32_t* __restrict__ hsa) {
  int i = blockIdx.x * 256 + threadIdx.x;        // 90112 threads
  int c = i % HROW;
  int grp = i / (NB * HROW), rem = i % (NB * HROW);
  uint32_t w = (c == 350) ? 0x3F800000u : 0u;
  hfa[(grp * 2 + 1) * NB * HROW + rem] = w;
  hsa[(grp * 2 + 1) * NB * HROW + rem] = w;
}

// ---- main: persistent, 2 decoupled waves per block, weights in regs ----
__global__ __launch_bounds__(128)
__attribute__((amdgpu_waves_per_eu(1, 1)))
void lstm_kernel(const short* __restrict__ xbf, const short* __restrict__ wswz,
                 uint32_t* __restrict__ hfa, uint32_t* __restrict__ hsa,
                 const float* __restrict__ dense_w, float* __restrict__ wpart) {
  __shared__ float lds_part[2][T_][16];   // 64 KB dense-head partials

  const int tid  = threadIdx.x;
  const int lane = tid & 63;
  const int wv   = tid >> 6;
  const int l15  = lane & 15;
  const int quad = lane >> 4;
  const int grp  = blockIdx.x & 15;     // round-robin => same-XCD heuristic
  const int j    = blockIdx.x >> 4;
  const int tileg = 2 * j + wv;

  // weights -> registers ONCE: 192 regs/lane
  short8 wreg[4][KC];
  #pragma unroll
  for (int g = 0; g < 4; ++g)
    #pragma unroll
    for (int kc = 0; kc < KC; ++kc)
      wreg[g][kc] = *(const short8*)(wswz +
          (((size_t)kc * NT + (g * 22 + tileg)) * 64 + lane) * 8);

  const int col = tileg * 16 + l15;
  const float dwv = (col < U_) ? dense_w[col] : 0.f;
  float cst[4] = {0.f, 0.f, 0.f, 0.f};

  const short* xrow = xbf + ((size_t)(grp * NB + l15) * T_) * F_ + quad * 8;
  uint32_t* hfb = hfa + (size_t)grp * 2 * NB * HROW;   // fast (sc0 / XCD-L2)
  uint32_t* hsb = hsa + (size_t)grp * 2 * NB * HROW;   // safe (agent / IF$)

  bool fast = true;

  #pragma unroll 1
  for (int t = 0; t < T_; ++t) {
    short8 axf = *(const short8*)(xrow + t * F_);

    // kc=0 (x-only) MFMA — h-independent
    float4_ acc[4];
    #pragma unroll
    for (int g = 0; g < 4; ++g) {
      float4_ z = (float4_){0.f, 0.f, 0.f, 0.f};
      acc[g] = __builtin_amdgcn_mfma_f32_16x16x32_bf16(axf, wreg[g][0], z, 0, 0, 0);
    }

    const uint32_t tv = (uint32_t)t & 0xFFFFu;
    const size_t rdoff = ((size_t)((t + 1) & 1)) * NB * HROW
                       + (size_t)l15 * HROW + quad * 8;
    u32x4 fq[22];

    if (fast) {
      const uint32_t* hq = hfb + rdoff;
      int tries = 0; bool okall;
      do {
        u32x4 f0,f1,f2,f3,f4,f5,f6,f7,f8,f9,f10,f11,f12,f13,f14,f15,f16,f17,f18,f19,f20,f21;
        asm volatile(
          "global_load_dwordx4 %0,  %22, off sc0\n\t"
          "global_load_dwordx4 %1,  %22, off offset:16 sc0\n\t"
          "global_load_dwordx4 %2,  %22, off offset:128 sc0\n\t"
          "global_load_dwordx4 %3,  %22, off offset:144 sc0\n\t"
          "global_load_dwordx4 %4,  %22, off offset:256 sc0\n\t"
          "global_load_dwordx4 %5,  %22, off offset:272 sc0\n\t"
          "global_load_dwordx4 %6,  %22, off offset:384 sc0\n\t"
          "global_load_dwordx4 %7,  %22, off offset:400 sc0\n\t"
          "global_load_dwordx4 %8,  %22, off offset:512 sc0\n\t"
          "global_load_dwordx4 %9,  %22, off offset:528 sc0\n\t"
          "global_load_dwordx4 %10, %22, off offset:640 sc0\n\t"
          "global_load_dwordx4 %11, %22, off offset:656 sc0\n\t"
          "global_load_dwordx4 %12, %22, off offset:768 sc0\n\t"
          "global_load_dwordx4 %13, %22, off offset:784 sc0\n\t"
          "global_load_dwordx4 %14, %22, off offset:896 sc0\n\t"
          "global_load_dwordx4 %15, %22, off offset:912 sc0\n\t"
          "global_load_dwordx4 %16, %22, off offset:1024 sc0\n\t"
          "global_load_dwordx4 %17, %22, off offset:1040 sc0\n\t"
          "global_load_dwordx4 %18, %22, off offset:1152 sc0\n\t"
          "global_load_dwordx4 %19, %22, off offset:1168 sc0\n\t"
          "global_load_dwordx4 %20, %22, off offset:1280 sc0\n\t"
          "global_load_dwordx4 %21, %22, off offset:1296 sc0\n\t"
          "s_waitcnt vmcnt(0)"
          : "=v"(f0),"=v"(f1),"=v"(f2),"=v"(f3),"=v"(f4),"=v"(f5),
            "=v"(f6),"=v"(f7),"=v"(f8),"=v"(f9),"=v"(f10),"=v"(f11),
            "=v"(f12),"=v"(f13),"=v"(f14),"=v"(f15),"=v"(f16),"=v"(f17),
            "=v"(f18),"=v"(f19),"=v"(f20),"=v"(f21)
          : "v"(hq) : "memory");
        fq[0]=f0; fq[1]=f1; fq[2]=f2; fq[3]=f3; fq[4]=f4; fq[5]=f5;
        fq[6]=f6; fq[7]=f7; fq[8]=f8; fq[9]=f9; fq[10]=f10; fq[11]=f11;
        fq[12]=f12; fq[13]=f13; fq[14]=f14; fq[15]=f15; fq[16]=f16;
        fq[17]=f17; fq[18]=f18; fq[19]=f19; fq[20]=f20; fq[21]=f21;
        uint32_t bad = 0;
        #pragma unroll
        for (int i = 0; i < 22; ++i) {
          u32x4 xo = fq[i] ^ tv;
          bad |= (xo[0] | xo[1] | xo[2] | xo[3]) & 0xFFFFu;
        }
        okall = (bool)__all((int)(bad == 0));
      } while (!okall && ++tries < MAXTRY);
      if (!okall) fast = false;         // sticky: placement is wrong
    }
    if (!fast) {
      // safe path: agent-scope tagged retry loop (always fresh via IF$)
      const uint32_t* hq = hsb + rdoff;
      bool okall;
      do {
        #pragma unroll
        for (int i = 0; i < 11; ++i) {
          const u64t* p = (const u64t*)(hq + i * 32);
          u64t q0 = __hip_atomic_load(p+0, __ATOMIC_RELAXED, __HIP_MEMORY_SCOPE_AGENT);
          u64t q1 = __hip_atomic_load(p+1, __ATOMIC_RELAXED, __HIP_MEMORY_SCOPE_AGENT);
          u64t q2 = __hip_atomic_load(p+2, __ATOMIC_RELAXED, __HIP_MEMORY_SCOPE_AGENT);
          u64t q3 = __hip_atomic_load(p+3, __ATOMIC_RELAXED, __HIP_MEMORY_SCOPE_AGENT);
          fq[2*i]   = (u32x4){(uint32_t)q0, (uint32_t)(q0>>32), (uint32_t)q1, (uint32_t)(q1>>32)};
          fq[2*i+1] = (u32x4){(uint32_t)q2, (uint32_t)(q2>>32), (uint32_t)q3, (uint32_t)(q3>>32)};
        }
        uint32_t bad = 0;
        #pragma unroll
        for (int i = 0; i < 22; ++i) {
          u32x4 xo = fq[i] ^ tv;
          bad |= (xo[0] | xo[1] | xo[2] | xo[3]) & 0xFFFFu;
        }
        okall = (bool)__all((int)(bad == 0));
      } while (!okall);
    }

    // repack hi16 pairs -> bf16 A-frags; MFMA over kc=1..11
    #pragma unroll
    for (int i = 0; i < 11; ++i) {
      union { uint32_t w[4]; short8 s; } u;
      #pragma unroll
      for (int k = 0; k < 4; ++k) {
        uint32_t lo = fq[2*i + (k>>1)][(k&1)*2];
        uint32_t hi = fq[2*i + (k>>1)][(k&1)*2 + 1];
        u.w[k] = (lo >> 16) | (hi & 0xFFFF0000u);
      }
      #pragma unroll
      for (int g = 0; g < 4; ++g)
        acc[g] = __builtin_amdgcn_mfma_f32_16x16x32_bf16(u.s, wreg[g][i + 1], acc[g], 0, 0, 0);
    }

    // gate update: lane covers rows quad*4+r at its col
    const uint32_t otag = (uint32_t)(t + 1) & 0xFFFFu;
    const size_t wroff = ((size_t)(t & 1)) * NB * HROW;
    float hn[4];
    #pragma unroll
    for (int r = 0; r < 4; ++r) {
      float ig = __builtin_amdgcn_rcpf(1.f + __expf(-acc[0][r]));
      float fg = __builtin_amdgcn_rcpf(1.f + __expf(-acc[1][r]));
      float gg = fmaxf(acc[2][r], 0.f);
      float og = __builtin_amdgcn_rcpf(1.f + __expf(-acc[3][r]));
      float cn = fg * cst[r] + ig * gg;
      cst[r] = cn;
      hn[r] = og * fmaxf(cn, 0.f);
      short hs = f2bf(hn[r]);
      if (col == 350) hs = (short)0x3F80;
      else if (col == 351) hs = 0;
      uint32_t word = ((uint32_t)(unsigned short)hs << 16) | otag;
      // fast publish: sc0 -> local/shared XCD L2 (fire-and-forget)
      uint32_t* fdst = hfb + wroff + (quad * 4 + r) * HROW + col;
      asm volatile("global_store_dword %0, %1, off sc0"
                   :: "v"(fdst), "v"(word) : "memory");
      // safe publish: agent scope -> coherence point (fire-and-forget)
      __hip_atomic_store(hsb + wroff + (quad * 4 + r) * HROW + col, word,
                         __ATOMIC_RELAXED, __HIP_MEMORY_SCOPE_AGENT);
    }

    // dense head (off the critical path), into LDS
    #pragma unroll
    for (int r = 0; r < 4; ++r) {
      float s = hn[r] * dwv;
      s += __shfl_xor(s, 1); s += __shfl_xor(s, 2);
      s += __shfl_xor(s, 4); s += __shfl_xor(s, 8);
      if (l15 == 0) lds_part[wv][t][quad * 4 + r] = s;
    }
  }

  __syncthreads();
  float* wp = wpart + ((size_t)(grp * NCB + j) * NB) * T_;
  for (int i = tid; i < NB * T_; i += 128) {
    int t = i & (T_ - 1), row = i >> 9;
    wp[(size_t)row * T_ + t] = lds_part[0][t][row] + lds_part[1][t][row];
  }
}

// ---- final: out[b,t] = db + sum_j wpart[grp][j][row][t] ----
__global__ void reduce_out(const float* __restrict__ wpart,
                           const float* __restrict__ dense_b,
                           float* __restrict__ out) {
  int i = blockIdx.x * 256 + threadIdx.x;
  int b = i >> 9, t = i & 511;
  int grp = b >> 4, row = b & 15;
  float s = dense_b[0];
  #pragma unroll
  for (int j = 0; j < NCB; ++j)
    s += wpart[(((size_t)grp * NCB + j) * NB + row) * T_ + t];
  out[i] = s;
}

extern "C" void kernel_launch(void* const* d_in, const int* in_sizes, int n_in,
                              void* d_out, int out_size, void* d_ws, size_t ws_size,
                              hipStream_t stream) {
  const float* x    = (const float*)d_in[0];
  const float* kern = (const float*)d_in[1];
  const float* rk   = (const float*)d_in[2];
  const float* bias = (const float*)d_in[3];
  const float* dw   = (const float*)d_in[4];
  const float* db   = (const float*)d_in[5];
  float* out = (float*)d_out;

  char* ws = (char*)d_ws;
  short*    wswz  = (short*)(ws);
  short*    xbf   = (short*)(ws + OFF_XBF);
  uint32_t* hfaB  = (uint32_t*)(ws + OFF_HFA);
  uint32_t* hsaB  = (uint32_t*)(ws + OFF_HSA);
  float*    wpart = (float*)(ws + OFF_WP);

  prep_w<<<NT, 64, 0, stream>>>(kern, rk, bias, wswz);
  prep_x<<<(256 * T_ * F_) / (256 * 4), 256, 0, stream>>>(x, xbf);
  init_all<<<(NGRP * NB * HROW) / 256, 256, 0, stream>>>(hfaB, hsaB);
  lstm_kernel<<<NGRP * NCB, 128, 0, stream>>>(xbf, wswz, hfaB, hsaB, dw, wpart);
  reduce_out<<<(256 * T_) / 256, 256, 0, stream>>>(wpart, db, out);
}